// Round 3
// baseline (429.519 us; speedup 1.0000x reference)
//
#include <hip/hip_runtime.h>
#include <hip/hip_fp16.h>

// Problem: out[M,N] = fp16( a[M,K] @ (w_q[K,N] * scale[K/G,N]) ), G=128.
// Harness dtype contract: fp16 tensors are passed/returned as FLOAT32.
// a: float32 [4096,4096], w_q: int32 [4096,4096], scale: float32 [32,4096],
// out: float32 [4096,4096].
#define MDIM 4096
#define NDIM 4096
#define KDIM 4096

#define BM 128
#define BN 128
#define BK 64
#define NT 256
#define STR 72  // LDS row stride in halfs: 144 B rows, 2-way bank alias only

typedef _Float16 f16x8 __attribute__((ext_vector_type(8)));
typedef float f32x4 __attribute__((ext_vector_type(4)));
typedef unsigned int u32;

__device__ inline __half2 as_half2(u32 u) {
  return __builtin_bit_cast(__half2, u);
}
__device__ inline u32 as_u32(__half2 h) { return __builtin_bit_cast(u32, h); }

__global__ __launch_bounds__(NT) void qgemm(
    const float* __restrict__ A,   // [M][K] f32 (fp16-representable values)
    const int* __restrict__ Wq,    // [K][N] int32 in [0,16)
    const float* __restrict__ Sc,  // [K/128][N] f32 (fp16-representable)
    float* __restrict__ C) {       // [M][N] f32

  __shared__ __align__(16) _Float16 As[BM * STR];  // [m][k+pad]
  __shared__ __align__(16) _Float16 Bs[BN * STR];  // [n][k+pad]

  const int tid = threadIdx.x;
  const int bx = blockIdx.x & 31;  // n-block
  const int by = blockIdx.x >> 5;  // m-block
  const int m_base = by * BM;
  const int n_base = bx * BN;

  const int wave = tid >> 6;
  const int lane = tid & 63;
  const int l15 = lane & 15;
  const int quad = lane >> 4;
  const int wm = (wave & 1) * 64;
  const int wn = (wave >> 1) * 64;

  // B staging: thread owns one n column, half the k range.
  const int bn_local = tid & 127;
  const int bk_half = (tid >> 7) * 8;  // 0 or 8
  const int gn = n_base + bn_local;

  f32x4 acc[4][4];
#pragma unroll
  for (int i = 0; i < 4; ++i)
#pragma unroll
    for (int j = 0; j < 4; ++j) acc[i][j] = (f32x4)0.0f;

  for (int kt = 0; kt < KDIM / BK; ++kt) {
    const int k0 = kt * BK;
    __syncthreads();  // previous tile's MFMA reads done before overwrite

    // ---- stage A: fp32 global -> fp16 LDS [m][k]. Coalesced float4. ----
    // 128x64 fp32 tile = 2048 float4 chunks; 8 rounds x 256 threads.
#pragma unroll
    for (int i = 0; i < 8; ++i) {
      const int c = i * 256 + tid;        // chunk id
      const int row = c >> 4;             // 16 chunks per 64-f32 row
      const int col4 = (c & 15) * 4;      // f32 col within row
      const float4 f =
          *(const float4*)(A + (size_t)(m_base + row) * KDIM + k0 + col4);
      // exact: values are fp16-representable
      __half2 lo = __floats2half2_rn(f.x, f.y);
      __half2 hi = __floats2half2_rn(f.z, f.w);
      u32 pk[2] = {as_u32(lo), as_u32(hi)};
      *(uint2*)&As[(size_t)row * STR + col4] = *(const uint2*)pk;
    }

    // ---- stage B: int32 -> dequant fp16 -> LDS [n][k] ----
    {
      const __half hs = __float2half(Sc[(size_t)(k0 >> 7) * NDIM + gn]);
      const __half2 s2 = __half2half2(hs);
      const __half2 nb2 = __half2half2(__hmul(hs, __float2half(-1024.0f)));
#pragma unroll
      for (int it = 0; it < 4; ++it) {
        const int k = bk_half + it * 16;  // 8 consecutive k per step
        u32 v[8];
#pragma unroll
        for (int j = 0; j < 8; ++j)
          v[j] = (u32)Wq[(size_t)(k0 + k + j) * NDIM + gn];
        u32 pk[4];
#pragma unroll
        for (int p = 0; p < 4; ++p) {
          // fp16 bits of (1024+v): 0x6400|v, exact for v in [0,16).
          // fma((1024+v), s, -1024*s) = RNE(v*s): bit-exact vs fp16 dequant.
          u32 u = v[2 * p] | (v[2 * p + 1] << 16) | 0x64006400u;
          pk[p] = as_u32(__hfma2(as_half2(u), s2, nb2));
        }
        *(uint4*)&Bs[(size_t)bn_local * STR + k] = *(const uint4*)pk;
      }
    }

    __syncthreads();

    // ---- MFMA: 2 k-steps of 32; A[m=l15][k=quad*8+j], B symmetric ----
#pragma unroll
    for (int ks = 0; ks < BK; ks += 32) {
      f16x8 af[4], bf[4];
#pragma unroll
      for (int i = 0; i < 4; ++i)
        af[i] = *(const f16x8*)&As[(size_t)(wm + i * 16 + l15) * STR + ks + quad * 8];
#pragma unroll
      for (int j = 0; j < 4; ++j)
        bf[j] = *(const f16x8*)&Bs[(size_t)(wn + j * 16 + l15) * STR + ks + quad * 8];
#pragma unroll
      for (int i = 0; i < 4; ++i)
#pragma unroll
        for (int j = 0; j < 4; ++j)
          acc[i][j] = __builtin_amdgcn_mfma_f32_16x16x32_f16(af[i], bf[j],
                                                             acc[i][j], 0, 0, 0);
    }
  }

  // ---- epilogue: C/D layout col=lane&15, row=quad*4+reg; fp16-round ----
#pragma unroll
  for (int i = 0; i < 4; ++i) {
#pragma unroll
    for (int j = 0; j < 4; ++j) {
      const int col = n_base + wn + j * 16 + l15;
#pragma unroll
      for (int r = 0; r < 4; ++r) {
        const int row = m_base + wm + i * 16 + quad * 4 + r;
        // match reference's fp16 output rounding, stored as f32
        C[(size_t)row * NDIM + col] = __half2float(__float2half(acc[i][j][r]));
      }
    }
  }
}

extern "C" void kernel_launch(void* const* d_in, const int* in_sizes, int n_in,
                              void* d_out, int out_size, void* d_ws, size_t ws_size,
                              hipStream_t stream) {
  const float* a = (const float*)d_in[0];
  const int* wq = (const int*)d_in[1];
  const float* sc = (const float*)d_in[2];
  float* out = (float*)d_out;

  dim3 grid((MDIM / BM) * (NDIM / BN));  // 1024 blocks, 32x32 tiles
  dim3 block(NT);
  qgemm<<<grid, block, 0, stream>>>(a, wq, sc, out);
}

// Round 5
// 356.218 us; speedup vs baseline: 1.2058x; 1.2058x over previous
//
#include <hip/hip_runtime.h>
#include <hip/hip_fp16.h>

// out[M,N] = fp16( a[M,K] @ (w_q[K,N] * scale[K/G,N]) ), G=128, all dims 4096.
// Harness dtype contract: fp16 tensors passed/returned as FLOAT32.
//   a: f32 [4096,4096], w_q: int32 [4096,4096], scale: f32 [32,4096],
//   out: f32 [4096,4096].
// Strategy: prepass A->fp16, prepass dequant+transpose W -> Wt fp16 [N][K]
// (both in d_ws), then m97-structure fp16 MFMA GEMM with global_load_lds.
#define MDIM 4096
#define NDIM 4096
#define KDIM 4096

#define BM 128
#define BN 128
#define BK 64
#define NT 256

typedef _Float16 f16x8 __attribute__((ext_vector_type(8)));
typedef float f32x4 __attribute__((ext_vector_type(4)));
typedef unsigned int u32;
typedef unsigned short u16;

__device__ inline __half2 as_half2(u32 u) { return __builtin_bit_cast(__half2, u); }
__device__ inline u32 as_u32(__half2 h) { return __builtin_bit_cast(u32, h); }
// __builtin_amdgcn_cvt_pkrtz returns __fp16 ext_vector(2); bit-cast that type.
__device__ inline u32 pkrtz(float a, float b) {
  return __builtin_bit_cast(u32, __builtin_amdgcn_cvt_pkrtz(a, b));
}

// async global -> LDS, 16 B/lane. LDS dst must be wave-uniform base + lane*16.
__device__ inline void load16_to_lds(const void* g, void* l) {
  __builtin_amdgcn_global_load_lds(
      (__attribute__((address_space(1))) const u32*)g,
      (__attribute__((address_space(3))) u32*)l,
      16, 0, 0);
}

// ---------------- pass 1: A fp32 -> fp16 (exact; RTZ==RNE here) ----------
__global__ __launch_bounds__(NT) void a_to_f16(const float* __restrict__ A,
                                               _Float16* __restrict__ A16) {
  const size_t base = ((size_t)blockIdx.x * NT + threadIdx.x) * 8;
  const float4 f0 = *(const float4*)(A + base);
  const float4 f1 = *(const float4*)(A + base + 4);
  u32 pk[4];
  pk[0] = pkrtz(f0.x, f0.y);
  pk[1] = pkrtz(f0.z, f0.w);
  pk[2] = pkrtz(f1.x, f1.y);
  pk[3] = pkrtz(f1.z, f1.w);
  *(uint4*)(A16 + base) = *(const uint4*)pk;
}

// ------- pass 2: dequant Wq [K][N] + transpose -> Wt fp16 [N][K] ---------
// 64x64 tiles; reads and writes both coalesced via LDS.
#define TSTR 68  // u16 stride, breaks bank alignment on transposed reads
__global__ __launch_bounds__(NT) void w_dequant_t(const int* __restrict__ Wq,
                                                  const float* __restrict__ Sc,
                                                  _Float16* __restrict__ Wt) {
  __shared__ __align__(16) u16 Ls[64 * TSTR];
  const int tid = threadIdx.x;
  const int n0 = (blockIdx.x & 63) * 64;
  const int k0 = (blockIdx.x >> 6) * 64;
  const int g = k0 >> 7;  // 64-tile lies within one 128-group

  // phase 1: coalesced read + dequant, LDS [k][n]
#pragma unroll
  for (int r = 0; r < 4; ++r) {
    const int c = r * 256 + tid;     // 0..1023
    const int krow = c >> 4;         // k within tile
    const int col4 = (c & 15) * 4;   // n within tile
    const int4 v = *(const int4*)(Wq + (size_t)(k0 + krow) * NDIM + n0 + col4);
    const float4 s = *(const float4*)(Sc + (size_t)g * NDIM + n0 + col4);
    // fp16 bits of (1024+v): 0x6400|v; hfma gives single-rounded v*s.
    __half2 s01 = __floats2half2_rn(s.x, s.y);
    __half2 s23 = __floats2half2_rn(s.z, s.w);
    const __half2 kneg = __half2half2(__float2half(-1024.0f));
    __half2 nb01 = __hmul2(s01, kneg), nb23 = __hmul2(s23, kneg);
    u32 u01 = (u32)v.x | ((u32)v.y << 16) | 0x64006400u;
    u32 u23 = (u32)v.z | ((u32)v.w << 16) | 0x64006400u;
    u32 pk[2];
    pk[0] = as_u32(__hfma2(as_half2(u01), s01, nb01));
    pk[1] = as_u32(__hfma2(as_half2(u23), s23, nb23));
    *(uint2*)&Ls[(size_t)krow * TSTR + col4] = *(const uint2*)pk;
  }
  __syncthreads();

  // phase 2: transposed read from LDS, coalesced 16B writes to Wt [n][k]
#pragma unroll
  for (int r = 0; r < 2; ++r) {
    const int idx = r * 256 + tid;   // 0..511
    const int n = idx >> 3;          // n within tile
    const int kc = (idx & 7) * 8;    // k chunk
    u16 tmp[8];
#pragma unroll
    for (int j = 0; j < 8; ++j) tmp[j] = Ls[(size_t)(kc + j) * TSTR + n];
    *(uint4*)(Wt + (size_t)(n0 + n) * KDIM + k0 + kc) = *(const uint4*)tmp;
  }
}

// ---------------- pass 3: m97-structure fp16 GEMM ------------------------
__global__ __launch_bounds__(NT) void gemm_f16(const _Float16* __restrict__ A16,
                                               const _Float16* __restrict__ Wt,
                                               float* __restrict__ C) {
  __shared__ __align__(16) _Float16 As[BM * BK];  // [m][k] 16 KB, no pad
  __shared__ __align__(16) _Float16 Bs[BN * BK];  // [n][k] 16 KB, no pad

  const int tid = threadIdx.x;
  const int bx = blockIdx.x & 31;  // n-block
  const int by = blockIdx.x >> 5;  // m-block
  const int m_base = by * BM;
  const int n_base = bx * BN;

  const int wave = tid >> 6;
  const int lane = tid & 63;
  const int l15 = lane & 15;
  const int quad = lane >> 4;
  const int wm = (wave & 1) * 64;
  const int wn = (wave >> 1) * 64;

  f32x4 acc[4][4];
#pragma unroll
  for (int i = 0; i < 4; ++i)
#pragma unroll
    for (int j = 0; j < 4; ++j) acc[i][j] = (f32x4)0.0f;

  for (int kt = 0; kt < KDIM / BK; ++kt) {
    const int k0 = kt * BK;
    __syncthreads();

    // stage A and B via global_load_lds: 4 chunks each per thread.
#pragma unroll
    for (int r = 0; r < 4; ++r) {
      const int c = r * 256 + tid;   // chunk 0..1023, 16 B each
      const int row = c >> 3;        // m (or n) within tile
      const int off = (c & 7) * 8;   // k offset in halfs
      load16_to_lds(A16 + (size_t)(m_base + row) * KDIM + k0 + off,
                    (char*)As + (size_t)c * 16);
      load16_to_lds(Wt + (size_t)(n_base + row) * KDIM + k0 + off,
                    (char*)Bs + (size_t)c * 16);
    }
    __syncthreads();

#pragma unroll
    for (int ks = 0; ks < BK; ks += 32) {
      f16x8 af[4], bf[4];
#pragma unroll
      for (int i = 0; i < 4; ++i)
        af[i] = *(const f16x8*)&As[(size_t)(wm + i * 16 + l15) * BK + ks + quad * 8];
#pragma unroll
      for (int j = 0; j < 4; ++j)
        bf[j] = *(const f16x8*)&Bs[(size_t)(wn + j * 16 + l15) * BK + ks + quad * 8];
#pragma unroll
      for (int i = 0; i < 4; ++i)
#pragma unroll
        for (int j = 0; j < 4; ++j)
          acc[i][j] = __builtin_amdgcn_mfma_f32_16x16x32_f16(af[i], bf[j],
                                                             acc[i][j], 0, 0, 0);
    }
  }

  // epilogue: C/D layout col=lane&15, row=quad*4+reg; fp16-round, store f32
#pragma unroll
  for (int i = 0; i < 4; ++i) {
#pragma unroll
    for (int j = 0; j < 4; ++j) {
      const int col = n_base + wn + j * 16 + l15;
#pragma unroll
      for (int r = 0; r < 4; ++r) {
        const int row = m_base + wm + i * 16 + quad * 4 + r;
        C[(size_t)row * NDIM + col] = __half2float(__float2half(acc[i][j][r]));
      }
    }
  }
}

// ---------------- fallback: round-3 fused kernel (passing, 331 us) -------
#define STR 72
__global__ __launch_bounds__(NT) void qgemm_fused(
    const float* __restrict__ A, const int* __restrict__ Wq,
    const float* __restrict__ Sc, float* __restrict__ C) {
  __shared__ __align__(16) _Float16 As[BM * STR];
  __shared__ __align__(16) _Float16 Bs[BN * STR];
  const int tid = threadIdx.x;
  const int bx = blockIdx.x & 31, by = blockIdx.x >> 5;
  const int m_base = by * BM, n_base = bx * BN;
  const int wave = tid >> 6, lane = tid & 63;
  const int l15 = lane & 15, quad = lane >> 4;
  const int wm = (wave & 1) * 64, wn = (wave >> 1) * 64;
  const int bn_local = tid & 127, bk_half = (tid >> 7) * 8;
  const int gn = n_base + bn_local;
  f32x4 acc[4][4];
#pragma unroll
  for (int i = 0; i < 4; ++i)
#pragma unroll
    for (int j = 0; j < 4; ++j) acc[i][j] = (f32x4)0.0f;
  for (int kt = 0; kt < KDIM / BK; ++kt) {
    const int k0 = kt * BK;
    __syncthreads();
#pragma unroll
    for (int i = 0; i < 8; ++i) {
      const int c = i * 256 + tid;
      const int row = c >> 4, col4 = (c & 15) * 4;
      const float4 f = *(const float4*)(A + (size_t)(m_base + row) * KDIM + k0 + col4);
      u32 pk[2];
      pk[0] = pkrtz(f.x, f.y);
      pk[1] = pkrtz(f.z, f.w);
      *(uint2*)&As[(size_t)row * STR + col4] = *(const uint2*)pk;
    }
    {
      const __half hs = __float2half(Sc[(size_t)(k0 >> 7) * NDIM + gn]);
      const __half2 s2 = __half2half2(hs);
      const __half2 nb2 = __half2half2(__hmul(hs, __float2half(-1024.0f)));
#pragma unroll
      for (int it = 0; it < 4; ++it) {
        const int k = bk_half + it * 16;
        u32 v[8];
#pragma unroll
        for (int j = 0; j < 8; ++j)
          v[j] = (u32)Wq[(size_t)(k0 + k + j) * NDIM + gn];
        u32 pk[4];
#pragma unroll
        for (int p = 0; p < 4; ++p) {
          u32 u = v[2 * p] | (v[2 * p + 1] << 16) | 0x64006400u;
          pk[p] = as_u32(__hfma2(as_half2(u), s2, nb2));
        }
        *(uint4*)&Bs[(size_t)bn_local * STR + k] = *(const uint4*)pk;
      }
    }
    __syncthreads();
#pragma unroll
    for (int ks = 0; ks < BK; ks += 32) {
      f16x8 af[4], bf[4];
#pragma unroll
      for (int i = 0; i < 4; ++i)
        af[i] = *(const f16x8*)&As[(size_t)(wm + i * 16 + l15) * STR + ks + quad * 8];
#pragma unroll
      for (int j = 0; j < 4; ++j)
        bf[j] = *(const f16x8*)&Bs[(size_t)(wn + j * 16 + l15) * STR + ks + quad * 8];
#pragma unroll
      for (int i = 0; i < 4; ++i)
#pragma unroll
        for (int j = 0; j < 4; ++j)
          acc[i][j] = __builtin_amdgcn_mfma_f32_16x16x32_f16(af[i], bf[j],
                                                             acc[i][j], 0, 0, 0);
    }
  }
#pragma unroll
  for (int i = 0; i < 4; ++i)
#pragma unroll
    for (int j = 0; j < 4; ++j) {
      const int col = n_base + wn + j * 16 + l15;
#pragma unroll
      for (int r = 0; r < 4; ++r) {
        const int row = m_base + wm + i * 16 + quad * 4 + r;
        C[(size_t)row * NDIM + col] = __half2float(__float2half(acc[i][j][r]));
      }
    }
}

extern "C" void kernel_launch(void* const* d_in, const int* in_sizes, int n_in,
                              void* d_out, int out_size, void* d_ws, size_t ws_size,
                              hipStream_t stream) {
  const float* a = (const float*)d_in[0];
  const int* wq = (const int*)d_in[1];
  const float* sc = (const float*)d_in[2];
  float* out = (float*)d_out;

  const size_t a16_bytes = (size_t)MDIM * KDIM * 2;  // 32 MiB
  const size_t wt_bytes = (size_t)NDIM * KDIM * 2;   // 32 MiB

  if (ws_size >= a16_bytes + wt_bytes) {
    _Float16* a16 = (_Float16*)d_ws;
    _Float16* wt = (_Float16*)((char*)d_ws + a16_bytes);
    a_to_f16<<<(MDIM * (size_t)KDIM) / (NT * 8), NT, 0, stream>>>(a, a16);
    w_dequant_t<<<(KDIM / 64) * (NDIM / 64), NT, 0, stream>>>(wq, sc, wt);
    gemm_f16<<<(MDIM / BM) * (NDIM / BN), NT, 0, stream>>>(a16, wt, out);
  } else {
    qgemm_fused<<<(MDIM / BM) * (NDIM / BN), NT, 0, stream>>>(a, wq, sc, out);
  }
}

// Round 6
// 321.965 us; speedup vs baseline: 1.3341x; 1.1064x over previous
//
#include <hip/hip_runtime.h>
#include <hip/hip_fp16.h>

// out[M,N] = fp16( a[M,K] @ (w_q[K,N] * scale[K/G,N]) ), G=128, all dims 4096.
// Harness dtype contract: fp16 tensors passed/returned as FLOAT32.
// Strategy: one fused prepass kernel (A f32->f16 copy + W dequant/transpose
// -> Wt f16 [N][K], both in d_ws), then m97-structure f16 MFMA GEMM with
// global_load_lds and XOR-swizzled LDS (conflict-free b128 fragment reads).
#define MDIM 4096
#define NDIM 4096
#define KDIM 4096

#define BM 128
#define BN 128
#define BK 64
#define NT 256

typedef _Float16 f16x8 __attribute__((ext_vector_type(8)));
typedef float f32x4 __attribute__((ext_vector_type(4)));
typedef unsigned int u32;
typedef unsigned short u16;

__device__ inline __half2 as_half2(u32 u) { return __builtin_bit_cast(__half2, u); }
__device__ inline u32 as_u32(__half2 h) { return __builtin_bit_cast(u32, h); }
// __builtin_amdgcn_cvt_pkrtz returns __fp16 ext_vector(2); bit-cast directly.
__device__ inline u32 pkrtz(float a, float b) {
  return __builtin_bit_cast(u32, __builtin_amdgcn_cvt_pkrtz(a, b));
}

// async global -> LDS, 16 B/lane. LDS dst must be wave-uniform base + lane*16.
__device__ inline void load16_to_lds(const void* g, void* l) {
  __builtin_amdgcn_global_load_lds(
      (__attribute__((address_space(1))) const u32*)g,
      (__attribute__((address_space(3))) u32*)l,
      16, 0, 0);
}

// ---- fused prepass: blocks [0,4096) dequant+transpose W, [4096,12288) A ----
#define TSTR 68  // u16 stride for transpose staging
#define WBLK 4096
__global__ __launch_bounds__(NT) void prep(const float* __restrict__ A,
                                           _Float16* __restrict__ A16,
                                           const int* __restrict__ Wq,
                                           const float* __restrict__ Sc,
                                           _Float16* __restrict__ Wt) {
  __shared__ __align__(16) u16 Ls[64 * TSTR];
  const int tid = threadIdx.x;

  if (blockIdx.x >= WBLK) {
    // ---- A fp32 -> fp16 (exact: values are fp16-representable) ----
    const size_t b = blockIdx.x - WBLK;
    const size_t base = (b * NT + tid) * 8;
    const float4 f0 = *(const float4*)(A + base);
    const float4 f1 = *(const float4*)(A + base + 4);
    u32 pk[4];
    pk[0] = pkrtz(f0.x, f0.y);
    pk[1] = pkrtz(f0.z, f0.w);
    pk[2] = pkrtz(f1.x, f1.y);
    pk[3] = pkrtz(f1.z, f1.w);
    *(uint4*)(A16 + base) = *(const uint4*)pk;
    return;
  }

  // ---- W: dequant Wq [K][N] + transpose -> Wt f16 [N][K], 64x64 tile ----
  const int n0 = (blockIdx.x & 63) * 64;
  const int k0 = (blockIdx.x >> 6) * 64;
  const int g = k0 >> 7;  // 64-tile lies within one 128-group

  // phase 1: coalesced read + dequant, LDS [k][n]
#pragma unroll
  for (int r = 0; r < 4; ++r) {
    const int c = r * 256 + tid;
    const int krow = c >> 4;
    const int col4 = (c & 15) * 4;
    const int4 v = *(const int4*)(Wq + (size_t)(k0 + krow) * NDIM + n0 + col4);
    const float4 s = *(const float4*)(Sc + (size_t)g * NDIM + n0 + col4);
    // fp16 bits of (1024+v): 0x6400|v; hfma gives single-rounded v*s.
    __half2 s01 = __floats2half2_rn(s.x, s.y);
    __half2 s23 = __floats2half2_rn(s.z, s.w);
    const __half2 kneg = __half2half2(__float2half(-1024.0f));
    __half2 nb01 = __hmul2(s01, kneg), nb23 = __hmul2(s23, kneg);
    u32 u01 = (u32)v.x | ((u32)v.y << 16) | 0x64006400u;
    u32 u23 = (u32)v.z | ((u32)v.w << 16) | 0x64006400u;
    u32 pk[2];
    pk[0] = as_u32(__hfma2(as_half2(u01), s01, nb01));
    pk[1] = as_u32(__hfma2(as_half2(u23), s23, nb23));
    *(uint2*)&Ls[(size_t)krow * TSTR + col4] = *(const uint2*)pk;
  }
  __syncthreads();

  // phase 2: transposed read from LDS, coalesced 16B writes to Wt [n][k]
#pragma unroll
  for (int r = 0; r < 2; ++r) {
    const int idx = r * 256 + tid;
    const int n = idx >> 3;
    const int kc = (idx & 7) * 8;
    u16 tmp[8];
#pragma unroll
    for (int j = 0; j < 8; ++j) tmp[j] = Ls[(size_t)(kc + j) * TSTR + n];
    *(uint4*)(Wt + (size_t)(n0 + n) * KDIM + k0 + kc) = *(const uint4*)tmp;
  }
}

// ---------------- m97-structure fp16 GEMM, XOR-swizzled LDS --------------
// Physical 16B chunk pcol in a row holds logical chunk pcol^(row&7).
// global_load_lds dst is lane-order-fixed, so the *global source* column is
// permuted per lane (same 128B segment per row -> still coalesced).
// Fragment b128 reads then hit all 32 banks balanced (8 words/bank).
__global__ __launch_bounds__(NT) void gemm_f16(const _Float16* __restrict__ A16,
                                               const _Float16* __restrict__ Wt,
                                               float* __restrict__ C) {
  __shared__ __align__(16) _Float16 As[BM * BK];  // [m][k] 16 KB, swizzled
  __shared__ __align__(16) _Float16 Bs[BN * BK];  // [n][k] 16 KB, swizzled

  const int tid = threadIdx.x;
  const int bx = blockIdx.x & 31;  // n-block
  const int by = blockIdx.x >> 5;  // m-block
  const int m_base = by * BM;
  const int n_base = bx * BN;

  const int wave = tid >> 6;
  const int lane = tid & 63;
  const int l15 = lane & 15;
  const int quad = lane >> 4;
  const int wm = (wave & 1) * 64;
  const int wn = (wave >> 1) * 64;

  f32x4 acc[4][4];
#pragma unroll
  for (int i = 0; i < 4; ++i)
#pragma unroll
    for (int j = 0; j < 4; ++j) acc[i][j] = (f32x4)0.0f;

  for (int kt = 0; kt < KDIM / BK; ++kt) {
    const int k0 = kt * BK;
    __syncthreads();

#pragma unroll
    for (int r = 0; r < 4; ++r) {
      const int c = r * 256 + tid;            // physical chunk 0..1023
      const int row = c >> 3;                 // m (or n) within tile
      const int gcol = (c & 7) ^ (row & 7);   // logical (global) chunk
      load16_to_lds(A16 + (size_t)(m_base + row) * KDIM + k0 + gcol * 8,
                    (char*)As + (size_t)c * 16);
      load16_to_lds(Wt + (size_t)(n_base + row) * KDIM + k0 + gcol * 8,
                    (char*)Bs + (size_t)c * 16);
    }
    __syncthreads();

#pragma unroll
    for (int ks = 0; ks < BK; ks += 32) {
      const int ksc = ks >> 3;  // logical chunk base (0 or 4)
      f16x8 af[4], bf[4];
#pragma unroll
      for (int i = 0; i < 4; ++i) {
        const int row = wm + i * 16 + l15;
        af[i] = *(const f16x8*)&As[((size_t)row * 8 +
                                    ((ksc + quad) ^ (row & 7))) * 8];
      }
#pragma unroll
      for (int j = 0; j < 4; ++j) {
        const int row = wn + j * 16 + l15;
        bf[j] = *(const f16x8*)&Bs[((size_t)row * 8 +
                                    ((ksc + quad) ^ (row & 7))) * 8];
      }
#pragma unroll
      for (int i = 0; i < 4; ++i)
#pragma unroll
        for (int j = 0; j < 4; ++j)
          acc[i][j] = __builtin_amdgcn_mfma_f32_16x16x32_f16(af[i], bf[j],
                                                             acc[i][j], 0, 0, 0);
    }
  }

  // epilogue: C/D layout col=lane&15, row=quad*4+reg; fp16-round, store f32
#pragma unroll
  for (int i = 0; i < 4; ++i) {
#pragma unroll
    for (int j = 0; j < 4; ++j) {
      const int col = n_base + wn + j * 16 + l15;
#pragma unroll
      for (int r = 0; r < 4; ++r) {
        const int row = m_base + wm + i * 16 + quad * 4 + r;
        C[(size_t)row * NDIM + col] = __half2float(__float2half(acc[i][j][r]));
      }
    }
  }
}

// ---------------- fallback: fused single-kernel (round-3, 331 us) --------
#define STR 72
__global__ __launch_bounds__(NT) void qgemm_fused(
    const float* __restrict__ A, const int* __restrict__ Wq,
    const float* __restrict__ Sc, float* __restrict__ C) {
  __shared__ __align__(16) _Float16 As[BM * STR];
  __shared__ __align__(16) _Float16 Bs[BN * STR];
  const int tid = threadIdx.x;
  const int bx = blockIdx.x & 31, by = blockIdx.x >> 5;
  const int m_base = by * BM, n_base = bx * BN;
  const int wave = tid >> 6, lane = tid & 63;
  const int l15 = lane & 15, quad = lane >> 4;
  const int wm = (wave & 1) * 64, wn = (wave >> 1) * 64;
  const int bn_local = tid & 127, bk_half = (tid >> 7) * 8;
  const int gn = n_base + bn_local;
  f32x4 acc[4][4];
#pragma unroll
  for (int i = 0; i < 4; ++i)
#pragma unroll
    for (int j = 0; j < 4; ++j) acc[i][j] = (f32x4)0.0f;
  for (int kt = 0; kt < KDIM / BK; ++kt) {
    const int k0 = kt * BK;
    __syncthreads();
#pragma unroll
    for (int i = 0; i < 8; ++i) {
      const int c = i * 256 + tid;
      const int row = c >> 4, col4 = (c & 15) * 4;
      const float4 f = *(const float4*)(A + (size_t)(m_base + row) * KDIM + k0 + col4);
      u32 pk[2];
      pk[0] = pkrtz(f.x, f.y);
      pk[1] = pkrtz(f.z, f.w);
      *(uint2*)&As[(size_t)row * STR + col4] = *(const uint2*)pk;
    }
    {
      const __half hs = __float2half(Sc[(size_t)(k0 >> 7) * NDIM + gn]);
      const __half2 s2 = __half2half2(hs);
      const __half2 nb2 = __half2half2(__hmul(hs, __float2half(-1024.0f)));
#pragma unroll
      for (int it = 0; it < 4; ++it) {
        const int k = bk_half + it * 16;
        u32 v[8];
#pragma unroll
        for (int j = 0; j < 8; ++j)
          v[j] = (u32)Wq[(size_t)(k0 + k + j) * NDIM + gn];
        u32 pk[4];
#pragma unroll
        for (int p = 0; p < 4; ++p) {
          u32 u = v[2 * p] | (v[2 * p + 1] << 16) | 0x64006400u;
          pk[p] = as_u32(__hfma2(as_half2(u), s2, nb2));
        }
        *(uint4*)&Bs[(size_t)bn_local * STR + k] = *(const uint4*)pk;
      }
    }
    __syncthreads();
#pragma unroll
    for (int ks = 0; ks < BK; ks += 32) {
      f16x8 af[4], bf[4];
#pragma unroll
      for (int i = 0; i < 4; ++i)
        af[i] = *(const f16x8*)&As[(size_t)(wm + i * 16 + l15) * STR + ks + quad * 8];
#pragma unroll
      for (int j = 0; j < 4; ++j)
        bf[j] = *(const f16x8*)&Bs[(size_t)(wn + j * 16 + l15) * STR + ks + quad * 8];
#pragma unroll
      for (int i = 0; i < 4; ++i)
#pragma unroll
        for (int j = 0; j < 4; ++j)
          acc[i][j] = __builtin_amdgcn_mfma_f32_16x16x32_f16(af[i], bf[j],
                                                             acc[i][j], 0, 0, 0);
    }
  }
#pragma unroll
  for (int i = 0; i < 4; ++i)
#pragma unroll
    for (int j = 0; j < 4; ++j) {
      const int col = n_base + wn + j * 16 + l15;
#pragma unroll
      for (int r = 0; r < 4; ++r) {
        const int row = m_base + wm + i * 16 + quad * 4 + r;
        C[(size_t)row * NDIM + col] = __half2float(__float2half(acc[i][j][r]));
      }
    }
}

extern "C" void kernel_launch(void* const* d_in, const int* in_sizes, int n_in,
                              void* d_out, int out_size, void* d_ws, size_t ws_size,
                              hipStream_t stream) {
  const float* a = (const float*)d_in[0];
  const int* wq = (const int*)d_in[1];
  const float* sc = (const float*)d_in[2];
  float* out = (float*)d_out;

  const size_t a16_bytes = (size_t)MDIM * KDIM * 2;  // 32 MiB
  const size_t wt_bytes = (size_t)NDIM * KDIM * 2;   // 32 MiB

  if (ws_size >= a16_bytes + wt_bytes) {
    _Float16* a16 = (_Float16*)d_ws;
    _Float16* wt = (_Float16*)((char*)d_ws + a16_bytes);
    const int a_blocks = (MDIM * KDIM) / (NT * 8);  // 8192
    prep<<<WBLK + a_blocks, NT, 0, stream>>>(a, a16, wq, sc, wt);
    gemm_f16<<<(MDIM / BM) * (NDIM / BN), NT, 0, stream>>>(a16, wt, out);
  } else {
    qgemm_fused<<<(MDIM / BM) * (NDIM / BN), NT, 0, stream>>>(a, wq, sc, out);
  }
}